// Round 1
// baseline (1020.208 us; speedup 1.0000x reference)
//
#include <hip/hip_runtime.h>
#include <hip/hip_bf16.h>

// Problem constants
constexpr int Cc  = 128;    // channels
constexpr int HWc = 784;    // 28*28
constexpr int Pc  = 2000;   // prototypes
constexpr int NC  = 200;    // classes

// Output offsets (floats)
constexpr long OFF_SCORE = 0;         // 16*200
constexpr long OFF_MD    = 3200;      // 16*2000
constexpr long OFF_CO    = 35200;     // 16*200
constexpr long OFF_SIM   = 38400;     // 16*2000*784
constexpr long OFF_SIME  = 25126400;  // 16*2000*784
constexpr long OFF_LOGE  = 50214400;  // 16*200

// ---------------------------------------------------------------------------
// small utility kernels
// ---------------------------------------------------------------------------
__global__ void k_init(float* a, int n, float val) {
    int i = blockIdx.x * blockDim.x + threadIdx.x;
    if (i < n) a[i] = val;
}

__global__ void k_p2(const float* __restrict__ pv, float* __restrict__ p2) {
    int p = blockIdx.x * blockDim.x + threadIdx.x;
    if (p >= Pc) return;
    const float4* row = (const float4*)(pv + (long)p * Cc);
    float s = 0.f;
    #pragma unroll
    for (int q = 0; q < Cc / 4; ++q) {
        float4 v = row[q];
        s += v.x * v.x + v.y * v.y + v.z * v.z + v.w * v.w;
    }
    p2[p] = s;
}

__global__ void k_x2(const float* __restrict__ x, float* __restrict__ x2, int NI) {
    int idx = blockIdx.x * blockDim.x + threadIdx.x;
    if (idx >= NI * HWc) return;
    int img = idx / HWc, hw = idx % HWc;
    const float* xi = x + (long)img * Cc * HWc + hw;
    float s = 0.f;
    #pragma unroll 8
    for (int c = 0; c < Cc; ++c) {
        float v = xi[(long)c * HWc];
        s = fmaf(v, v, s);
    }
    x2[idx] = s;
}

// ---------------------------------------------------------------------------
// generic tiled fp32 GEMM: C = A * B  (per-image batch via blockIdx.z)
// AT=false: A is K x M (A[k*M+m]);  AT=true: A is M x K (A[m*K+k])
// BT=false: B is K x N;             BT=true: B is N x K
// C is M x N row-major. M,N,K multiples of 4; K multiple of 16.
// ---------------------------------------------------------------------------
template <bool AT, bool BT>
__global__ __launch_bounds__(256) void k_gemm64(
    const float* __restrict__ A, long strideA,
    const float* __restrict__ B, long strideB,
    float* __restrict__ Cout, long strideC,
    int M, int N, int K)
{
    __shared__ float As[16][68];
    __shared__ float Bs[16][68];
    const int img = blockIdx.z;
    A += (long)img * strideA;
    B += (long)img * strideB;
    Cout += (long)img * strideC;
    const int m0 = blockIdx.y * 64, n0 = blockIdx.x * 64;
    const int tx = threadIdx.x, ty = threadIdx.y;
    const int tid = ty * 16 + tx;
    float acc[4][4] = {};

    for (int k0 = 0; k0 < K; k0 += 16) {
        if (!AT) {
            int k = tid / 16, m = (tid % 16) * 4;
            float4 v = make_float4(0.f, 0.f, 0.f, 0.f);
            if (m0 + m < M) v = *(const float4*)(A + (long)(k0 + k) * M + m0 + m);
            As[k][m] = v.x; As[k][m + 1] = v.y; As[k][m + 2] = v.z; As[k][m + 3] = v.w;
        } else {
            int m = tid / 4, k = (tid % 4) * 4;
            float4 v = make_float4(0.f, 0.f, 0.f, 0.f);
            if (m0 + m < M) v = *(const float4*)(A + (long)(m0 + m) * K + k0 + k);
            As[k][m] = v.x; As[k + 1][m] = v.y; As[k + 2][m] = v.z; As[k + 3][m] = v.w;
        }
        if (!BT) {
            int k = tid / 16, n = (tid % 16) * 4;
            float4 v = make_float4(0.f, 0.f, 0.f, 0.f);
            if (n0 + n < N) v = *(const float4*)(B + (long)(k0 + k) * N + n0 + n);
            Bs[k][n] = v.x; Bs[k][n + 1] = v.y; Bs[k][n + 2] = v.z; Bs[k][n + 3] = v.w;
        } else {
            int n = tid / 4, k = (tid % 4) * 4;
            float4 v = make_float4(0.f, 0.f, 0.f, 0.f);
            if (n0 + n < N) v = *(const float4*)(B + (long)(n0 + n) * K + k0 + k);
            Bs[k][n] = v.x; Bs[k + 1][n] = v.y; Bs[k + 2][n] = v.z; Bs[k + 3][n] = v.w;
        }
        __syncthreads();
        #pragma unroll
        for (int kk = 0; kk < 16; ++kk) {
            float a[4], b[4];
            #pragma unroll
            for (int i = 0; i < 4; ++i) a[i] = As[kk][ty * 4 + i];
            #pragma unroll
            for (int j = 0; j < 4; ++j) b[j] = Bs[kk][tx * 4 + j];
            #pragma unroll
            for (int i = 0; i < 4; ++i)
                #pragma unroll
                for (int j = 0; j < 4; ++j)
                    acc[i][j] = fmaf(a[i], b[j], acc[i][j]);
        }
        __syncthreads();
    }

    #pragma unroll
    for (int i = 0; i < 4; ++i) {
        int m = m0 + ty * 4 + i;
        if (m < M) {
            #pragma unroll
            for (int j = 0; j < 4; ++j) {
                int n = n0 + tx * 4 + j;
                if (n < N) Cout[(long)m * N + n] = acc[i][j];
            }
        }
    }
}

// ---------------------------------------------------------------------------
// column softmax over axis i of A2[n,i,j] (stride HWc), out to separate buffer
// ---------------------------------------------------------------------------
__global__ __launch_bounds__(256) void k_smax_col(const float* __restrict__ A2,
                                                  float* __restrict__ Aout) {
    const int n = blockIdx.y;
    const int j = blockIdx.x * 32 + threadIdx.x;
    const int ty = threadIdx.y;
    const bool ok = j < HWc;
    __shared__ float red[8][33];
    const float* src = A2 + (long)n * HWc * HWc;
    float* dst = Aout + (long)n * HWc * HWc;

    float m = -1e30f;
    for (int i = ty; i < HWc; i += 8)
        if (ok) m = fmaxf(m, src[(long)i * HWc + j]);
    red[ty][threadIdx.x] = m;
    __syncthreads();
    if (ty == 0) {
        float mm = red[0][threadIdx.x];
        #pragma unroll
        for (int t = 1; t < 8; ++t) mm = fmaxf(mm, red[t][threadIdx.x]);
        red[0][threadIdx.x] = mm;
    }
    __syncthreads();
    m = red[0][threadIdx.x];
    __syncthreads();

    float s = 0.f;
    for (int i = ty; i < HWc; i += 8) {
        if (ok) {
            float e = __expf(src[(long)i * HWc + j] - m);
            dst[(long)i * HWc + j] = e;
            s += e;
        }
    }
    red[ty][threadIdx.x] = s;
    __syncthreads();
    if (ty == 0) {
        float ss = 0.f;
        #pragma unroll
        for (int t = 0; t < 8; ++t) ss += red[t][threadIdx.x];
        red[0][threadIdx.x] = ss;
    }
    __syncthreads();
    float inv = 1.f / red[0][threadIdx.x];
    for (int i = ty; i < HWc; i += 8)
        if (ok) dst[(long)i * HWc + j] *= inv;
}

// ---------------------------------------------------------------------------
// in-place row softmax over axis j of A2[n,i,j] (contiguous)
// ---------------------------------------------------------------------------
__global__ __launch_bounds__(256) void k_smax_row(float* __restrict__ A2) {
    float* row = A2 + ((long)blockIdx.y * HWc + blockIdx.x) * HWc;
    const int tid = threadIdx.x;
    const bool ok = tid < HWc / 4;  // 196
    __shared__ float red[4];

    float4 v = make_float4(-1e30f, -1e30f, -1e30f, -1e30f);
    if (ok) v = ((const float4*)row)[tid];
    float m = fmaxf(fmaxf(v.x, v.y), fmaxf(v.z, v.w));
    #pragma unroll
    for (int o = 1; o < 64; o <<= 1) m = fmaxf(m, __shfl_xor(m, o, 64));
    if ((tid & 63) == 0) red[tid >> 6] = m;
    __syncthreads();
    m = fmaxf(fmaxf(red[0], red[1]), fmaxf(red[2], red[3]));
    __syncthreads();

    float4 e;
    e.x = ok ? __expf(v.x - m) : 0.f;
    e.y = ok ? __expf(v.y - m) : 0.f;
    e.z = ok ? __expf(v.z - m) : 0.f;
    e.w = ok ? __expf(v.w - m) : 0.f;
    float s = e.x + e.y + e.z + e.w;
    #pragma unroll
    for (int o = 1; o < 64; o <<= 1) s += __shfl_xor(s, o, 64);
    if ((tid & 63) == 0) red[tid >> 6] = s;
    __syncthreads();
    s = red[0] + red[1] + red[2] + red[3];
    float inv = 1.f / s;
    if (ok) {
        e.x *= inv; e.y *= inv; e.z *= inv; e.w *= inv;
        ((float4*)row)[tid] = e;
    }
}

// ---------------------------------------------------------------------------
// classifier core: xp GEMM + d = relu(x2 - 2xp + p2), sim = exp(-d/256),
// min over hw via shuffle + atomicMin (md pre-initialized to 1e30)
// ---------------------------------------------------------------------------
__global__ __launch_bounds__(256) void k_l2(
    const float* __restrict__ x,    // NI x C x HW
    const float* __restrict__ pv,   // P x C
    const float* __restrict__ p2,   // P
    const float* __restrict__ x2,   // NI x HW
    float* __restrict__ sim,        // base or nullptr; img stride P*HW
    float* __restrict__ md)         // base; img stride P (pre-init 1e30)
{
    __shared__ float As[16][68];
    __shared__ float Bs[16][68];
    const int img = blockIdx.z;
    const float* xi = x + (long)img * Cc * HWc;
    const int p0 = blockIdx.y * 64, h0 = blockIdx.x * 64;
    const int tx = threadIdx.x, ty = threadIdx.y;
    const int tid = ty * 16 + tx;
    float acc[4][4] = {};

    for (int k0 = 0; k0 < Cc; k0 += 16) {
        {   // protos tile (M x K layout, transpose into LDS)
            int m = tid / 4, k = (tid % 4) * 4;
            float4 v = make_float4(0.f, 0.f, 0.f, 0.f);
            if (p0 + m < Pc) v = *(const float4*)(pv + (long)(p0 + m) * Cc + k0 + k);
            As[k][m] = v.x; As[k + 1][m] = v.y; As[k + 2][m] = v.z; As[k + 3][m] = v.w;
        }
        {   // x tile (K x N layout, direct)
            int k = tid / 16, n = (tid % 16) * 4;
            float4 v = make_float4(0.f, 0.f, 0.f, 0.f);
            if (h0 + n < HWc) v = *(const float4*)(xi + (long)(k0 + k) * HWc + h0 + n);
            Bs[k][n] = v.x; Bs[k][n + 1] = v.y; Bs[k][n + 2] = v.z; Bs[k][n + 3] = v.w;
        }
        __syncthreads();
        #pragma unroll
        for (int kk = 0; kk < 16; ++kk) {
            float a[4], b[4];
            #pragma unroll
            for (int i = 0; i < 4; ++i) a[i] = As[kk][ty * 4 + i];
            #pragma unroll
            for (int j = 0; j < 4; ++j) b[j] = Bs[kk][tx * 4 + j];
            #pragma unroll
            for (int i = 0; i < 4; ++i)
                #pragma unroll
                for (int j = 0; j < 4; ++j)
                    acc[i][j] = fmaf(a[i], b[j], acc[i][j]);
        }
        __syncthreads();
    }

    const float* x2i = x2 + (long)img * HWc;
    float dmin[4] = {1e30f, 1e30f, 1e30f, 1e30f};
    #pragma unroll
    for (int i = 0; i < 4; ++i) {
        int p = p0 + ty * 4 + i;
        bool okp = p < Pc;
        float p2v = okp ? p2[p] : 0.f;
        #pragma unroll
        for (int j = 0; j < 4; ++j) {
            int hw = h0 + tx * 4 + j;
            bool okh = hw < HWc;
            float xv = okh ? x2i[hw] : 0.f;
            float d = fmaxf(fmaf(-2.f, acc[i][j], xv + p2v), 0.f);
            if (okh) {
                dmin[i] = fminf(dmin[i], d);
                if (sim != nullptr && okp)
                    sim[(long)img * Pc * HWc + (long)p * HWc + hw] = __expf(d * (-1.f / 256.f));
            }
        }
    }
    // min-reduce over tx (16 lanes within a wave)
    #pragma unroll
    for (int i = 0; i < 4; ++i) {
        float v = dmin[i];
        v = fminf(v, __shfl_xor(v, 1, 64));
        v = fminf(v, __shfl_xor(v, 2, 64));
        v = fminf(v, __shfl_xor(v, 4, 64));
        v = fminf(v, __shfl_xor(v, 8, 64));
        dmin[i] = v;
    }
    if (tx == 0) {
        #pragma unroll
        for (int i = 0; i < 4; ++i) {
            int p = p0 + ty * 4 + i;
            if (p < Pc)
                atomicMin((int*)(md + (long)img * Pc + p), __float_as_int(dmin[i]));
        }
    }
}

// ---------------------------------------------------------------------------
// logits: act = exp(-md/256); out[img,c] = sum_p act[p]*w[c,p]
// ---------------------------------------------------------------------------
__global__ __launch_bounds__(256) void k_logits(
    const float* __restrict__ md, long md_stride,
    const float* __restrict__ w,   // NC x P
    float* __restrict__ out, long out_stride)
{
    const int img = blockIdx.x;
    __shared__ __align__(16) float act[Pc];
    const float* mrow = md + (long)img * md_stride;
    for (int p = threadIdx.x; p < Pc; p += 256)
        act[p] = __expf(mrow[p] * (-1.f / 256.f));
    __syncthreads();
    const int c = threadIdx.x;
    if (c < NC) {
        const float4* wrow = (const float4*)(w + (long)c * Pc);
        const float4* arow = (const float4*)act;
        float s = 0.f;
        for (int q = 0; q < Pc / 4; ++q) {
            float4 wv = wrow[q];
            float4 av = arow[q];
            s += wv.x * av.x + wv.y * av.y + wv.z * av.z + wv.w * av.w;
        }
        out[(long)img * out_stride + c] = s;
    }
}

// ---------------------------------------------------------------------------
extern "C" void kernel_launch(void* const* d_in, const int* in_sizes, int n_in,
                              void* d_out, int out_size, void* d_ws, size_t ws_size,
                              hipStream_t stream) {
    const float* f1    = (const float*)d_in[0];
    const float* f2    = (const float*)d_in[1];
    const float* faug  = (const float*)d_in[2];
    const float* prot  = (const float*)d_in[3];
    const float* prote = (const float*)d_in[4];
    const float* wl    = (const float*)d_in[5];
    const float* wle   = (const float*)d_in[6];
    float* out = (float*)d_out;
    float* ws  = (float*)d_ws;

    // workspace layout (floats)
    float* A2buf = ws;                     // 8*784*784 = 4917248
    float* Abuf  = ws + 4917248;           // 8*784*784
    float* fatt  = ws + 9834496;           // [16][128][784]: f1_att (0-7), f2_att (8-15)
    float* x2all = ws + 11440128;          // 48*784: f1, f2, att1, att2, aug
    float* p2    = ws + 11477760;          // 2000
    float* p2e   = ws + 11479760;          // 2000
    float* mdatt = ws + 11481760;          // 16*2000
    float* mdaug = ws + 11513760;          // 16*2000

    float* f1_att = fatt;
    float* f2_att = fatt + (long)8 * Cc * HWc;

    // init min-distance accumulators
    k_init<<<(32000 + 255) / 256, 256, 0, stream>>>(out + OFF_MD, 32000, 1e30f);
    k_init<<<(32000 + 255) / 256, 256, 0, stream>>>(mdatt, 32000, 1e30f);
    k_init<<<(32000 + 255) / 256, 256, 0, stream>>>(mdaug, 32000, 1e30f);

    // squared norms
    k_p2<<<(Pc + 255) / 256, 256, 0, stream>>>(prot, p2);
    k_p2<<<(Pc + 255) / 256, 256, 0, stream>>>(prote, p2e);
    k_x2<<<(8 * HWc + 255) / 256, 256, 0, stream>>>(f1, x2all, 8);
    k_x2<<<(8 * HWc + 255) / 256, 256, 0, stream>>>(f2, x2all + 8 * HWc, 8);
    k_x2<<<(16 * HWc + 255) / 256, 256, 0, stream>>>(faug, x2all + 32 * HWc, 16);

    dim3 b16(16, 16);
    // A2 = f1^T f2  (per n): A is KxM (c-major), B is KxN
    k_gemm64<false, false><<<dim3(13, 13, 8), b16, 0, stream>>>(
        f1, (long)Cc * HWc, f2, (long)Cc * HWc, A2buf, (long)HWc * HWc, HWc, HWc, Cc);
    // A = softmax over i (columns); Brow = softmax over j (rows, in-place)
    k_smax_col<<<dim3(25, 8), dim3(32, 8), 0, stream>>>(A2buf, Abuf);
    k_smax_row<<<dim3(HWc, 8), 256, 0, stream>>>(A2buf);
    // f2_att = f1 @ A      (A: MxK, B: KxN)
    k_gemm64<true, false><<<dim3(13, 2, 8), b16, 0, stream>>>(
        f1, (long)Cc * HWc, Abuf, (long)HWc * HWc, f2_att, (long)Cc * HWc, Cc, HWc, HWc);
    // f1_att = f2 @ Brow^T (A: MxK, B: NxK)
    k_gemm64<true, true><<<dim3(13, 2, 8), b16, 0, stream>>>(
        f2, (long)Cc * HWc, A2buf, (long)HWc * HWc, f1_att, (long)Cc * HWc, Cc, HWc, HWc);
    k_x2<<<(16 * HWc + 255) / 256, 256, 0, stream>>>(fatt, x2all + 16 * HWc, 16);

    // classifiers
    dim3 g8(13, 32, 8), g16(13, 32, 16);
    k_l2<<<g8, b16, 0, stream>>>(f1, prot, p2, x2all,
                                 out + OFF_SIM, out + OFF_MD);
    k_l2<<<g8, b16, 0, stream>>>(f2, prot, p2, x2all + 8 * HWc,
                                 out + OFF_SIM + (long)8 * Pc * HWc, out + OFF_MD + 8 * Pc);
    k_l2<<<g8, b16, 0, stream>>>(f1_att, prot, p2, x2all + 16 * HWc,
                                 nullptr, mdatt);
    k_l2<<<g8, b16, 0, stream>>>(f2_att, prot, p2, x2all + 24 * HWc,
                                 nullptr, mdatt + 8 * Pc);
    k_l2<<<g16, b16, 0, stream>>>(faug, prote, p2e, x2all + 32 * HWc,
                                  out + OFF_SIME, mdaug);

    // logits
    k_logits<<<8, 256, 0, stream>>>(out + OFF_MD, Pc, wl, out + OFF_SCORE, NC);
    k_logits<<<8, 256, 0, stream>>>(out + OFF_MD + 8 * Pc, Pc, wl, out + OFF_SCORE + 8 * NC, NC);
    k_logits<<<8, 256, 0, stream>>>(mdatt, Pc, wl, out + OFF_CO, NC);
    k_logits<<<8, 256, 0, stream>>>(mdatt + 8 * Pc, Pc, wl, out + OFF_CO + 8 * NC, NC);
    k_logits<<<16, 256, 0, stream>>>(mdaug, Pc, wle, out + OFF_LOGE, NC);
}

// Round 3
// 699.044 us; speedup vs baseline: 1.4594x; 1.4594x over previous
//
#include <hip/hip_runtime.h>
#include <hip/hip_bf16.h>

typedef unsigned short u16;
typedef unsigned int   u32;
typedef __attribute__((ext_vector_type(8))) short  bf16x8;
typedef __attribute__((ext_vector_type(8))) u16    u16x8;
typedef __attribute__((ext_vector_type(4))) float  f32x4;

// Problem constants
constexpr int Cc  = 128;    // channels
constexpr int HWc = 784;    // 28*28
constexpr int Pc  = 2000;   // prototypes
constexpr int NCc = 200;    // classes

// Output offsets (floats)
constexpr long OFF_SCORE = 0;         // 16*200
constexpr long OFF_MD    = 3200;      // 16*2000
constexpr long OFF_CO    = 35200;     // 16*200
constexpr long OFF_SIM   = 38400;     // 16*2000*784
constexpr long OFF_SIME  = 25126400;  // 16*2000*784
constexpr long OFF_LOGE  = 50214400;  // 16*200

__device__ inline u16 bf16_rne(float v) {
    u32 u = __float_as_uint(v);
    return (u16)((u + 0x7FFFu + ((u >> 16) & 1u)) >> 16);
}
__device__ inline float bf16_f(u16 b) { return __uint_as_float(((u32)b) << 16); }

// ---------------------------------------------------------------------------
// utilities
// ---------------------------------------------------------------------------
__global__ void k_init3(float* a, float* b, float* c, int n, float val) {
    int i = blockIdx.x * blockDim.x + threadIdx.x;
    if (i < n) { a[i] = val; b[i] = val; c[i] = val; }
}

__global__ void k_p2(const float* __restrict__ pa, const float* __restrict__ pb,
                     float* __restrict__ oa, float* __restrict__ ob) {
    int p = blockIdx.x * blockDim.x + threadIdx.x;
    if (p >= 2 * Pc) return;
    bool e = p >= Pc;
    int pp = e ? p - Pc : p;
    const float4* row = (const float4*)((e ? pb : pa) + (long)pp * Cc);
    float s = 0.f;
    #pragma unroll
    for (int q = 0; q < Cc / 4; ++q) {
        float4 v = row[q];
        s += v.x * v.x + v.y * v.y + v.z * v.z + v.w * v.w;
    }
    (e ? ob : oa)[pp] = s;
}

__global__ void k_cvt_prot(const float* __restrict__ p, const float* __restrict__ pe,
                           u16* __restrict__ phi, u16* __restrict__ plo,
                           u16* __restrict__ phie, u16* __restrict__ ploe) {
    int i = blockIdx.x * blockDim.x + threadIdx.x;
    const int n = Pc * Cc;
    if (i >= 2 * n) return;
    bool e = i >= n;
    int j = e ? i - n : i;
    float v = (e ? pe : p)[j];
    u16 h = bf16_rne(v);
    u16 l = bf16_rne(v - bf16_f(h));
    (e ? phie : phi)[j] = h;
    (e ? ploe : plo)[j] = l;
}

__global__ void k_x2(const float* __restrict__ x, float* __restrict__ x2, int NI) {
    int idx = blockIdx.x * blockDim.x + threadIdx.x;
    if (idx >= NI * HWc) return;
    int img = idx / HWc, hw = idx % HWc;
    const float* xi = x + (long)img * Cc * HWc + hw;
    float s = 0.f;
    #pragma unroll 8
    for (int c = 0; c < Cc; ++c) {
        float v = xi[(long)c * HWc];
        s = fmaf(v, v, s);
    }
    x2[idx] = s;
}

// transpose-convert: x [NI][C][HW] fp32 -> xhi/xlo [NI][HW][C] bf16 hi/lo
__global__ __launch_bounds__(256) void k_cvt_x(const float* __restrict__ x,
                                               u16* __restrict__ xhi,
                                               u16* __restrict__ xlo) {
    __shared__ float t[32][33];
    const int img = blockIdx.z;
    const int hw0 = blockIdx.x * 32, c0 = blockIdx.y * 32;
    const int tx = threadIdx.x, ty = threadIdx.y;  // 32 x 8
    const float* xi = x + (size_t)img * Cc * HWc;
    #pragma unroll
    for (int r = 0; r < 4; ++r) {
        int c = c0 + ty + r * 8;
        int hw = hw0 + tx;
        t[ty + r * 8][tx] = (hw < HWc) ? xi[(size_t)c * HWc + hw] : 0.f;
    }
    __syncthreads();
    const size_t ob = (size_t)img * HWc * Cc;
    #pragma unroll
    for (int r = 0; r < 4; ++r) {
        int hw = hw0 + ty + r * 8;
        int c = c0 + tx;
        if (hw < HWc) {
            float v = t[tx][ty + r * 8];
            u16 h = bf16_rne(v);
            u16 l = bf16_rne(v - bf16_f(h));
            xhi[ob + (size_t)hw * Cc + c] = h;
            xlo[ob + (size_t)hw * Cc + c] = l;
        }
    }
}

// ---------------------------------------------------------------------------
// generic tiled fp32 GEMM (attention path)
// ---------------------------------------------------------------------------
template <bool AT, bool BT>
__global__ __launch_bounds__(256) void k_gemm64(
    const float* __restrict__ A, long strideA,
    const float* __restrict__ B, long strideB,
    float* __restrict__ Cout, long strideC,
    int M, int N, int K)
{
    __shared__ float As[16][68];
    __shared__ float Bs[16][68];
    const int img = blockIdx.z;
    A += (long)img * strideA;
    B += (long)img * strideB;
    Cout += (long)img * strideC;
    const int m0 = blockIdx.y * 64, n0 = blockIdx.x * 64;
    const int tx = threadIdx.x, ty = threadIdx.y;
    const int tid = ty * 16 + tx;
    float acc[4][4] = {};

    for (int k0 = 0; k0 < K; k0 += 16) {
        if (!AT) {
            int k = tid / 16, m = (tid % 16) * 4;
            float4 v = make_float4(0.f, 0.f, 0.f, 0.f);
            if (m0 + m < M) v = *(const float4*)(A + (long)(k0 + k) * M + m0 + m);
            As[k][m] = v.x; As[k][m + 1] = v.y; As[k][m + 2] = v.z; As[k][m + 3] = v.w;
        } else {
            int m = tid / 4, k = (tid % 4) * 4;
            float4 v = make_float4(0.f, 0.f, 0.f, 0.f);
            if (m0 + m < M) v = *(const float4*)(A + (long)(m0 + m) * K + k0 + k);
            As[k][m] = v.x; As[k + 1][m] = v.y; As[k + 2][m] = v.z; As[k + 3][m] = v.w;
        }
        if (!BT) {
            int k = tid / 16, n = (tid % 16) * 4;
            float4 v = make_float4(0.f, 0.f, 0.f, 0.f);
            if (n0 + n < N) v = *(const float4*)(B + (long)(k0 + k) * N + n0 + n);
            Bs[k][n] = v.x; Bs[k][n + 1] = v.y; Bs[k][n + 2] = v.z; Bs[k][n + 3] = v.w;
        } else {
            int n = tid / 4, k = (tid % 4) * 4;
            float4 v = make_float4(0.f, 0.f, 0.f, 0.f);
            if (n0 + n < N) v = *(const float4*)(B + (long)(n0 + n) * K + k0 + k);
            Bs[k][n] = v.x; Bs[k + 1][n] = v.y; Bs[k + 2][n] = v.z; Bs[k + 3][n] = v.w;
        }
        __syncthreads();
        #pragma unroll
        for (int kk = 0; kk < 16; ++kk) {
            float a[4], b[4];
            #pragma unroll
            for (int i = 0; i < 4; ++i) a[i] = As[kk][ty * 4 + i];
            #pragma unroll
            for (int j = 0; j < 4; ++j) b[j] = Bs[kk][tx * 4 + j];
            #pragma unroll
            for (int i = 0; i < 4; ++i)
                #pragma unroll
                for (int j = 0; j < 4; ++j)
                    acc[i][j] = fmaf(a[i], b[j], acc[i][j]);
        }
        __syncthreads();
    }

    #pragma unroll
    for (int i = 0; i < 4; ++i) {
        int m = m0 + ty * 4 + i;
        if (m < M) {
            #pragma unroll
            for (int j = 0; j < 4; ++j) {
                int n = n0 + tx * 4 + j;
                if (n < N) Cout[(long)m * N + n] = acc[i][j];
            }
        }
    }
}

// ---------------------------------------------------------------------------
// softmaxes
// ---------------------------------------------------------------------------
__global__ __launch_bounds__(256) void k_smax_col(const float* __restrict__ A2,
                                                  float* __restrict__ Aout) {
    const int n = blockIdx.y;
    const int j = blockIdx.x * 32 + threadIdx.x;
    const int ty = threadIdx.y;
    const bool ok = j < HWc;
    __shared__ float red[8][33];
    const float* src = A2 + (long)n * HWc * HWc;
    float* dst = Aout + (long)n * HWc * HWc;

    float m = -1e30f;
    for (int i = ty; i < HWc; i += 8)
        if (ok) m = fmaxf(m, src[(long)i * HWc + j]);
    red[ty][threadIdx.x] = m;
    __syncthreads();
    if (ty == 0) {
        float mm = red[0][threadIdx.x];
        #pragma unroll
        for (int t = 1; t < 8; ++t) mm = fmaxf(mm, red[t][threadIdx.x]);
        red[0][threadIdx.x] = mm;
    }
    __syncthreads();
    m = red[0][threadIdx.x];
    __syncthreads();

    float s = 0.f;
    for (int i = ty; i < HWc; i += 8) {
        if (ok) {
            float e = __expf(src[(long)i * HWc + j] - m);
            dst[(long)i * HWc + j] = e;
            s += e;
        }
    }
    red[ty][threadIdx.x] = s;
    __syncthreads();
    if (ty == 0) {
        float ss = 0.f;
        #pragma unroll
        for (int t = 0; t < 8; ++t) ss += red[t][threadIdx.x];
        red[0][threadIdx.x] = ss;
    }
    __syncthreads();
    float inv = 1.f / red[0][threadIdx.x];
    for (int i = ty; i < HWc; i += 8)
        if (ok) dst[(long)i * HWc + j] *= inv;
}

__global__ __launch_bounds__(256) void k_smax_row(float* __restrict__ A2) {
    float* row = A2 + ((long)blockIdx.y * HWc + blockIdx.x) * HWc;
    const int tid = threadIdx.x;
    const bool ok = tid < HWc / 4;  // 196
    __shared__ float red[4];

    float4 v = make_float4(-1e30f, -1e30f, -1e30f, -1e30f);
    if (ok) v = ((const float4*)row)[tid];
    float m = fmaxf(fmaxf(v.x, v.y), fmaxf(v.z, v.w));
    #pragma unroll
    for (int o = 1; o < 64; o <<= 1) m = fmaxf(m, __shfl_xor(m, o, 64));
    if ((tid & 63) == 0) red[tid >> 6] = m;
    __syncthreads();
    m = fmaxf(fmaxf(red[0], red[1]), fmaxf(red[2], red[3]));
    __syncthreads();

    float4 e;
    e.x = ok ? __expf(v.x - m) : 0.f;
    e.y = ok ? __expf(v.y - m) : 0.f;
    e.z = ok ? __expf(v.z - m) : 0.f;
    e.w = ok ? __expf(v.w - m) : 0.f;
    float s = e.x + e.y + e.z + e.w;
    #pragma unroll
    for (int o = 1; o < 64; o <<= 1) s += __shfl_xor(s, o, 64);
    if ((tid & 63) == 0) red[tid >> 6] = s;
    __syncthreads();
    s = red[0] + red[1] + red[2] + red[3];
    float inv = 1.f / s;
    if (ok) {
        e.x *= inv; e.y *= inv; e.z *= inv; e.w *= inv;
        ((float4*)row)[tid] = e;
    }
}

// ---------------------------------------------------------------------------
// MFMA split-bf16 classifier: all 48 images in one dispatch.
// xp = Ahi*Bhi + Ahi*Blo + Alo*Bhi (fp32 acc); d = relu(x2 - 2xp + p2);
// sim = exp(-d/256) (imgs 0-15, 32-47); md via shuffle-min + atomicMin.
// Tile: 128(P) x 112(HW), K=128 in two 64-chunks; LDS 60KB, 2 blocks/CU.
// ---------------------------------------------------------------------------
__global__ __launch_bounds__(256, 2) void k_l2_mfma(
    const u16* __restrict__ xthi, const u16* __restrict__ xtlo,  // [48][784][128]
    const u16* __restrict__ phi,  const u16* __restrict__ plo,   // [2000][128]
    const u16* __restrict__ phie, const u16* __restrict__ ploe,
    const float* __restrict__ p2,  const float* __restrict__ p2e,
    const float* __restrict__ x2all,                              // [48][784]
    float* __restrict__ out, float* __restrict__ mdatt, float* __restrict__ mdaug)
{
    __shared__ u16 As[2][128][64];   // comp, m-row, k (16B-chunk XOR swizzled)
    __shared__ u16 Bs[2][112][64];   // comp, n-row, k
    const int img = blockIdx.z;
    const int p0 = blockIdx.y * 128;
    const int n0 = blockIdx.x * 112;
    const int tid = threadIdx.x;
    const int wid = tid >> 6, lane = tid & 63;
    const int lhi = lane >> 4, llo = lane & 15;

    const u16* pA0 = (img < 32) ? phi : phie;
    const u16* pA1 = (img < 32) ? plo : ploe;
    const u16* pB0 = xthi + (size_t)img * HWc * Cc;
    const u16* pB1 = xtlo + (size_t)img * HWc * Cc;

    f32x4 acc[2][7];
    #pragma unroll
    for (int s = 0; s < 2; ++s)
        #pragma unroll
        for (int n = 0; n < 7; ++n)
            acc[s][n] = f32x4{0.f, 0.f, 0.f, 0.f};

    for (int kc = 0; kc < 2; ++kc) {
        const int k0 = kc * 64;
        if (kc) __syncthreads();
        // stage A: 2 comps x 128 rows x 8 chunks of 16B = 2048 chunk-loads
        #pragma unroll
        for (int j = 0; j < 8; ++j) {
            int idx = tid + j * 256;
            int chunk = idx & 7, row = (idx >> 3) & 127, comp = idx >> 10;
            u16x8 v = {0, 0, 0, 0, 0, 0, 0, 0};
            int p = p0 + row;
            if (p < Pc) {
                const u16* src = comp ? pA1 : pA0;
                v = *(const u16x8*)(src + (size_t)p * Cc + k0 + chunk * 8);
            }
            *(u16x8*)&As[comp][row][(chunk ^ (row & 7)) * 8] = v;
        }
        // stage B: 2 x 112 x 8 = 1792 chunk-loads
        #pragma unroll
        for (int j = 0; j < 7; ++j) {
            int idx = tid + j * 256;
            int chunk = idx & 7, row = (idx >> 3) % 112, comp = idx / 896;
            const u16* src = comp ? pB1 : pB0;
            u16x8 v = *(const u16x8*)(src + (size_t)(n0 + row) * Cc + k0 + chunk * 8);
            *(u16x8*)&Bs[comp][row][(chunk ^ (row & 7)) * 8] = v;
        }
        __syncthreads();
        #pragma unroll
        for (int ks = 0; ks < 2; ++ks) {
            bf16x8 ah[2], al[2];
            #pragma unroll
            for (int s = 0; s < 2; ++s) {
                int row = wid * 32 + s * 16 + llo;
                int ch = (ks * 4 + lhi) ^ (row & 7);
                ah[s] = *(const bf16x8*)&As[0][row][ch * 8];
                al[s] = *(const bf16x8*)&As[1][row][ch * 8];
            }
            #pragma unroll
            for (int ni = 0; ni < 7; ++ni) {
                int row = ni * 16 + llo;
                int ch = (ks * 4 + lhi) ^ (row & 7);
                bf16x8 bh = *(const bf16x8*)&Bs[0][row][ch * 8];
                bf16x8 bl = *(const bf16x8*)&Bs[1][row][ch * 8];
                #pragma unroll
                for (int s = 0; s < 2; ++s) {
                    acc[s][ni] = __builtin_amdgcn_mfma_f32_16x16x32_bf16(ah[s], bh, acc[s][ni], 0, 0, 0);
                    acc[s][ni] = __builtin_amdgcn_mfma_f32_16x16x32_bf16(ah[s], bl, acc[s][ni], 0, 0, 0);
                    acc[s][ni] = __builtin_amdgcn_mfma_f32_16x16x32_bf16(al[s], bh, acc[s][ni], 0, 0, 0);
                }
            }
        }
    }

    // epilogue
    const float* x2i = x2all + (long)img * HWc;
    const float* p2p = (img < 32) ? p2 : p2e;
    float* simp = nullptr;
    if (img < 16) simp = out + OFF_SIM + (size_t)img * Pc * HWc;
    else if (img >= 32) simp = out + OFF_SIME + (size_t)(img - 32) * Pc * HWc;
    float* mdp = (img < 16) ? out + OFF_MD + (long)img * Pc
               : (img < 32) ? mdatt + (long)(img - 16) * Pc
                            : mdaug + (long)(img - 32) * Pc;

    #pragma unroll
    for (int s = 0; s < 2; ++s) {
        const int mbase = p0 + wid * 32 + s * 16 + lhi * 4;
        float p2v[4], dmin[4];
        bool mok[4];
        #pragma unroll
        for (int r = 0; r < 4; ++r) {
            int m = mbase + r;
            mok[r] = m < Pc;
            p2v[r] = mok[r] ? p2p[m] : 0.f;
            dmin[r] = 1e30f;
        }
        #pragma unroll
        for (int ni = 0; ni < 7; ++ni) {
            int hw = n0 + ni * 16 + llo;
            float x2v = x2i[hw];
            #pragma unroll
            for (int r = 0; r < 4; ++r) {
                float d = fmaxf(fmaf(-2.f, acc[s][ni][r], x2v + p2v[r]), 0.f);
                dmin[r] = fminf(dmin[r], d);
                if (simp != nullptr && mok[r])
                    simp[(size_t)(mbase + r) * HWc + hw] = __expf(d * (-1.f / 256.f));
            }
        }
        #pragma unroll
        for (int r = 0; r < 4; ++r) {
            float v = dmin[r];
            v = fminf(v, __shfl_xor(v, 1, 64));
            v = fminf(v, __shfl_xor(v, 2, 64));
            v = fminf(v, __shfl_xor(v, 4, 64));
            v = fminf(v, __shfl_xor(v, 8, 64));
            if (llo == 0 && mok[r])
                atomicMin((int*)(mdp + mbase + r), __float_as_int(v));
        }
    }
}

// ---------------------------------------------------------------------------
// all 48 logits rows in one dispatch
// ---------------------------------------------------------------------------
__global__ __launch_bounds__(256) void k_logits_all(
    float* __restrict__ out,
    const float* __restrict__ mdatt, const float* __restrict__ mdaug,
    const float* __restrict__ wl, const float* __restrict__ wle)
{
    const int b = blockIdx.x;
    const float* md; const float* w; float* dst;
    if (b < 16)      { md = out + OFF_MD + (long)b * Pc;          w = wl;  dst = out + OFF_SCORE + (long)b * NCc; }
    else if (b < 32) { md = mdatt + (long)(b - 16) * Pc;          w = wl;  dst = out + OFF_CO + (long)(b - 16) * NCc; }
    else             { md = mdaug + (long)(b - 32) * Pc;          w = wle; dst = out + OFF_LOGE + (long)(b - 32) * NCc; }

    __shared__ __align__(16) float act[Pc];
    for (int p = threadIdx.x; p < Pc; p += 256)
        act[p] = __expf(md[p] * (-1.f / 256.f));
    __syncthreads();
    const int c = threadIdx.x;
    if (c < NCc) {
        const float4* wrow = (const float4*)(w + (long)c * Pc);
        const float4* arow = (const float4*)act;
        float s = 0.f;
        for (int q = 0; q < Pc / 4; ++q) {
            float4 wv = wrow[q];
            float4 av = arow[q];
            s += wv.x * av.x + wv.y * av.y + wv.z * av.z + wv.w * av.w;
        }
        dst[c] = s;
    }
}

// ---------------------------------------------------------------------------
extern "C" void kernel_launch(void* const* d_in, const int* in_sizes, int n_in,
                              void* d_out, int out_size, void* d_ws, size_t ws_size,
                              hipStream_t stream) {
    const float* f1    = (const float*)d_in[0];
    const float* f2    = (const float*)d_in[1];
    const float* faug  = (const float*)d_in[2];
    const float* prot  = (const float*)d_in[3];
    const float* prote = (const float*)d_in[4];
    const float* wl    = (const float*)d_in[5];
    const float* wle   = (const float*)d_in[6];
    float* out = (float*)d_out;
    float* ws  = (float*)d_ws;

    // workspace layout (float offsets)
    float* A2buf = ws;                      // 8*784*784
    float* Abuf  = ws + 4917248;            // 8*784*784
    float* fatt  = ws + 9834496;            // 16*128*784 (f1_att 0-7, f2_att 8-15)
    float* x2all = ws + 11440128;           // 48*784
    float* p2    = ws + 11477760;           // 2000
    float* p2e   = ws + 11479760;           // 2000
    float* mdatt = ws + 11481760;           // 16*2000
    float* mdaug = ws + 11513760;           // 16*2000
    u16* phi  = (u16*)(ws + 11545760);      // 2000*128
    u16* plo  = (u16*)(ws + 11673760);
    u16* phie = (u16*)(ws + 11801760);
    u16* ploe = (u16*)(ws + 11929760);
    u16* xthi = (u16*)(ws + 12057760);      // 48*784*128
    u16* xtlo = (u16*)(ws + 14466208);

    float* f1_att = fatt;

    constexpr size_t IS = (size_t)HWc * Cc;  // per-image bf16 stride

    // init md accumulators
    k_init3<<<(32000 + 255) / 256, 256, 0, stream>>>(out + OFF_MD, mdatt, mdaug, 32000, 1e30f);
    // proto norms + conversions
    k_p2<<<(2 * Pc + 255) / 256, 256, 0, stream>>>(prot, prote, p2, p2e);
    k_cvt_prot<<<(2 * Pc * Cc + 255) / 256, 256, 0, stream>>>(prot, prote, phi, plo, phie, ploe);
    // x norms
    k_x2<<<(8 * HWc + 255) / 256, 256, 0, stream>>>(f1, x2all, 8);
    k_x2<<<(8 * HWc + 255) / 256, 256, 0, stream>>>(f2, x2all + 8 * HWc, 8);
    k_x2<<<(16 * HWc + 255) / 256, 256, 0, stream>>>(faug, x2all + 32 * HWc, 16);
    // x conversions (transpose to [img][hw][c], bf16 hi/lo)
    dim3 cb(32, 8);
    k_cvt_x<<<dim3(25, 4, 8), cb, 0, stream>>>(f1, xthi, xtlo);
    k_cvt_x<<<dim3(25, 4, 8), cb, 0, stream>>>(f2, xthi + 8 * IS, xtlo + 8 * IS);
    k_cvt_x<<<dim3(25, 4, 16), cb, 0, stream>>>(faug, xthi + 32 * IS, xtlo + 32 * IS);

    // ---- attention path (fp32) ----
    dim3 b16(16, 16);
    k_gemm64<false, false><<<dim3(13, 13, 8), b16, 0, stream>>>(
        f1, (long)Cc * HWc, f2, (long)Cc * HWc, A2buf, (long)HWc * HWc, HWc, HWc, Cc);
    k_smax_col<<<dim3(25, 8), dim3(32, 8), 0, stream>>>(A2buf, Abuf);
    k_smax_row<<<dim3(HWc, 8), 256, 0, stream>>>(A2buf);
    // f2_att = f1 @ A
    k_gemm64<true, false><<<dim3(13, 2, 8), b16, 0, stream>>>(
        f1, (long)Cc * HWc, Abuf, (long)HWc * HWc, fatt + (long)8 * Cc * HWc, (long)Cc * HWc, Cc, HWc, HWc);
    // f1_att = f2 @ Brow^T
    k_gemm64<true, true><<<dim3(13, 2, 8), b16, 0, stream>>>(
        f2, (long)Cc * HWc, A2buf, (long)HWc * HWc, f1_att, (long)Cc * HWc, Cc, HWc, HWc);
    k_x2<<<(16 * HWc + 255) / 256, 256, 0, stream>>>(fatt, x2all + 16 * HWc, 16);
    k_cvt_x<<<dim3(25, 4, 16), cb, 0, stream>>>(fatt, xthi + 16 * IS, xtlo + 16 * IS);

    // ---- fused MFMA classifier over all 48 images ----
    k_l2_mfma<<<dim3(7, 16, 48), 256, 0, stream>>>(
        xthi, xtlo, phi, plo, phie, ploe, p2, p2e, x2all, out, mdatt, mdaug);

    // ---- logits ----
    k_logits_all<<<48, 256, 0, stream>>>(out, mdatt, mdaug, wl, wle);
}

// Round 8
// 522.900 us; speedup vs baseline: 1.9511x; 1.3369x over previous
//
#include <hip/hip_runtime.h>
#include <hip/hip_bf16.h>

typedef unsigned short u16;
typedef unsigned int   u32;
typedef __attribute__((ext_vector_type(8))) short  bf16x8;
typedef __attribute__((ext_vector_type(8))) u16    u16x8;
typedef __attribute__((ext_vector_type(4))) float  f32x4;

// Problem constants
constexpr int Cc  = 128;    // channels
constexpr int HWc = 784;    // 28*28
constexpr int Pc  = 2000;   // prototypes
constexpr int NCc = 200;    // classes

// Output offsets (floats)
constexpr long OFF_SCORE = 0;         // 16*200
constexpr long OFF_MD    = 3200;      // 16*2000
constexpr long OFF_CO    = 35200;     // 16*200
constexpr long OFF_SIM   = 38400;     // 16*2000*784
constexpr long OFF_SIME  = 25126400;  // 16*2000*784
constexpr long OFF_LOGE  = 50214400;  // 16*200

__device__ inline u16 bf16_rne(float v) {
    u32 u = __float_as_uint(v);
    return (u16)((u + 0x7FFFu + ((u >> 16) & 1u)) >> 16);
}
__device__ inline float bf16_f(u16 b) { return __uint_as_float(((u32)b) << 16); }

// ---------------------------------------------------------------------------
// utilities
// ---------------------------------------------------------------------------
__global__ void k_init3(float* a, float* b, float* c, int n, float val) {
    int i = blockIdx.x * blockDim.x + threadIdx.x;
    if (i < n) { a[i] = val; b[i] = val; c[i] = val; }
}

__global__ void k_p2(const float* __restrict__ pa, const float* __restrict__ pb,
                     float* __restrict__ oa, float* __restrict__ ob) {
    int p = blockIdx.x * blockDim.x + threadIdx.x;
    if (p >= 2 * Pc) return;
    bool e = p >= Pc;
    int pp = e ? p - Pc : p;
    const float4* row = (const float4*)((e ? pb : pa) + (long)pp * Cc);
    float s = 0.f;
    #pragma unroll
    for (int q = 0; q < Cc / 4; ++q) {
        float4 v = row[q];
        s += v.x * v.x + v.y * v.y + v.z * v.z + v.w * v.w;
    }
    (e ? ob : oa)[pp] = s;
}

__global__ void k_cvt_prot(const float* __restrict__ p, const float* __restrict__ pe,
                           u16* __restrict__ phi, u16* __restrict__ plo,
                           u16* __restrict__ phie, u16* __restrict__ ploe) {
    int i = blockIdx.x * blockDim.x + threadIdx.x;
    const int n = Pc * Cc;
    if (i >= 2 * n) return;
    bool e = i >= n;
    int j = e ? i - n : i;
    float v = (e ? pe : p)[j];
    u16 h = bf16_rne(v);
    u16 l = bf16_rne(v - bf16_f(h));
    (e ? phie : phi)[j] = h;
    (e ? ploe : plo)[j] = l;
}

__global__ void k_x2(const float* __restrict__ x, float* __restrict__ x2, int NI) {
    int idx = blockIdx.x * blockDim.x + threadIdx.x;
    if (idx >= NI * HWc) return;
    int img = idx / HWc, hw = idx % HWc;
    const float* xi = x + (long)img * Cc * HWc + hw;
    float s = 0.f;
    #pragma unroll 8
    for (int c = 0; c < Cc; ++c) {
        float v = xi[(long)c * HWc];
        s = fmaf(v, v, s);
    }
    x2[idx] = s;
}

// transpose-convert: x [NI][C][HW] fp32 -> xhi/xlo [NI][HW][C] bf16 hi/lo
__global__ __launch_bounds__(256) void k_cvt_x(const float* __restrict__ x,
                                               u16* __restrict__ xhi,
                                               u16* __restrict__ xlo) {
    __shared__ float t[32][33];
    const int img = blockIdx.z;
    const int hw0 = blockIdx.x * 32, c0 = blockIdx.y * 32;
    const int tx = threadIdx.x, ty = threadIdx.y;  // 32 x 8
    const float* xi = x + (size_t)img * Cc * HWc;
    #pragma unroll
    for (int r = 0; r < 4; ++r) {
        int c = c0 + ty + r * 8;
        int hw = hw0 + tx;
        t[ty + r * 8][tx] = (hw < HWc) ? xi[(size_t)c * HWc + hw] : 0.f;
    }
    __syncthreads();
    const size_t ob = (size_t)img * HWc * Cc;
    #pragma unroll
    for (int r = 0; r < 4; ++r) {
        int hw = hw0 + ty + r * 8;
        int c = c0 + tx;
        if (hw < HWc) {
            float v = t[tx][ty + r * 8];
            u16 h = bf16_rne(v);
            u16 l = bf16_rne(v - bf16_f(h));
            xhi[ob + (size_t)hw * Cc + c] = h;
            xlo[ob + (size_t)hw * Cc + c] = l;
        }
    }
}

// flat convert: f1,f2 [8][C][HW] fp32 -> Fb hi/lo [16][C][HW] bf16 (slots 0-7 f1, 8-15 f2)
__global__ void k_cvt_flat4(const float4* __restrict__ a, const float4* __restrict__ b,
                            ushort4* __restrict__ hi, ushort4* __restrict__ lo, int nper4) {
    int i = blockIdx.x * blockDim.x + threadIdx.x;
    if (i >= 2 * nper4) return;
    float4 v = (i < nper4) ? a[i] : b[i - nper4];
    ushort4 h, l;
    h.x = bf16_rne(v.x); l.x = bf16_rne(v.x - bf16_f(h.x));
    h.y = bf16_rne(v.y); l.y = bf16_rne(v.y - bf16_f(h.y));
    h.z = bf16_rne(v.z); l.z = bf16_rne(v.z - bf16_f(h.z));
    h.w = bf16_rne(v.w); l.w = bf16_rne(v.w - bf16_f(h.w));
    hi[i] = h; lo[i] = l;
}

// ---------------------------------------------------------------------------
// A2 pair via MFMA split-bf16: z<8: A2[img] = Xt1 . Xt2^T; z>=8: A2T[img] = Xt2 . Xt1^T
// Xt = [hw][c] bf16 hi/lo. Output fp32 [784][784]. Tile 128(m) x 112(n), K=128.
// ---------------------------------------------------------------------------
__global__ __launch_bounds__(256, 2) void k_a2_mfma(
    const u16* __restrict__ xthi, const u16* __restrict__ xtlo,
    float* __restrict__ A2, float* __restrict__ A2T)
{
    __shared__ u16 As[2][128][64];
    __shared__ u16 Bs[2][112][64];
    const int z = blockIdx.z;
    const int aimg = z, bimg = (z < 8) ? z + 8 : z - 8;
    float* C = ((z < 8) ? A2 : A2T) + (size_t)(z & 7) * HWc * HWc;
    const int m0 = blockIdx.y * 128, n0 = blockIdx.x * 112;
    const int tid = threadIdx.x;
    const int wid = tid >> 6, lane = tid & 63;
    const int lhi = lane >> 4, llo = lane & 15;

    const u16* pA0 = xthi + (size_t)aimg * HWc * Cc;
    const u16* pA1 = xtlo + (size_t)aimg * HWc * Cc;
    const u16* pB0 = xthi + (size_t)bimg * HWc * Cc;
    const u16* pB1 = xtlo + (size_t)bimg * HWc * Cc;

    f32x4 acc[2][7];
    #pragma unroll
    for (int s = 0; s < 2; ++s)
        #pragma unroll
        for (int n = 0; n < 7; ++n)
            acc[s][n] = f32x4{0.f, 0.f, 0.f, 0.f};

    for (int kc = 0; kc < 2; ++kc) {
        const int k0 = kc * 64;
        if (kc) __syncthreads();
        #pragma unroll
        for (int j = 0; j < 8; ++j) {
            int idx = tid + j * 256;
            int chunk = idx & 7, row = (idx >> 3) & 127, comp = idx >> 10;
            u16x8 v = {0, 0, 0, 0, 0, 0, 0, 0};
            if (m0 + row < HWc) {
                const u16* src = comp ? pA1 : pA0;
                v = *(const u16x8*)(src + (size_t)(m0 + row) * Cc + k0 + chunk * 8);
            }
            *(u16x8*)&As[comp][row][(chunk ^ (row & 7)) * 8] = v;
        }
        #pragma unroll
        for (int j = 0; j < 7; ++j) {
            int idx = tid + j * 256;
            int chunk = idx & 7, row = (idx >> 3) % 112, comp = idx / 896;
            const u16* src = comp ? pB1 : pB0;
            u16x8 v = *(const u16x8*)(src + (size_t)(n0 + row) * Cc + k0 + chunk * 8);
            *(u16x8*)&Bs[comp][row][(chunk ^ (row & 7)) * 8] = v;
        }
        __syncthreads();
        #pragma unroll
        for (int ks = 0; ks < 2; ++ks) {
            bf16x8 ah[2], al[2];
            #pragma unroll
            for (int s = 0; s < 2; ++s) {
                int row = wid * 32 + s * 16 + llo;
                int ch = (ks * 4 + lhi) ^ (row & 7);
                ah[s] = *(const bf16x8*)&As[0][row][ch * 8];
                al[s] = *(const bf16x8*)&As[1][row][ch * 8];
            }
            #pragma unroll
            for (int ni = 0; ni < 7; ++ni) {
                int row = ni * 16 + llo;
                int ch = (ks * 4 + lhi) ^ (row & 7);
                bf16x8 bh = *(const bf16x8*)&Bs[0][row][ch * 8];
                bf16x8 bl = *(const bf16x8*)&Bs[1][row][ch * 8];
                #pragma unroll
                for (int s = 0; s < 2; ++s) {
                    acc[s][ni] = __builtin_amdgcn_mfma_f32_16x16x32_bf16(ah[s], bh, acc[s][ni], 0, 0, 0);
                    acc[s][ni] = __builtin_amdgcn_mfma_f32_16x16x32_bf16(ah[s], bl, acc[s][ni], 0, 0, 0);
                    acc[s][ni] = __builtin_amdgcn_mfma_f32_16x16x32_bf16(al[s], bh, acc[s][ni], 0, 0, 0);
                }
            }
        }
    }

    #pragma unroll
    for (int s = 0; s < 2; ++s) {
        #pragma unroll
        for (int r = 0; r < 4; ++r) {
            int m = m0 + wid * 32 + s * 16 + lhi * 4 + r;
            if (m < HWc) {
                #pragma unroll
                for (int ni = 0; ni < 7; ++ni) {
                    int n = n0 + ni * 16 + llo;
                    C[(size_t)m * HWc + n] = acc[s][ni][r];
                }
            }
        }
    }
}

// ---------------------------------------------------------------------------
// row softmax -> bf16 hi/lo. z=0: A2 -> SR; z=1: A2T -> ST.
// ---------------------------------------------------------------------------
__global__ __launch_bounds__(256) void k_smax_row_bf16(
    const float* __restrict__ A2, const float* __restrict__ A2T,
    u16* __restrict__ SRhi, u16* __restrict__ SRlo,
    u16* __restrict__ SThi, u16* __restrict__ STlo)
{
    const int which = blockIdx.z;
    const size_t off = ((size_t)blockIdx.y * HWc + blockIdx.x) * HWc;
    const float* row = (which ? A2T : A2) + off;
    u16* dhi = (which ? SThi : SRhi) + off;
    u16* dlo = (which ? STlo : SRlo) + off;
    const int tid = threadIdx.x;
    const bool ok = tid < HWc / 4;  // 196
    __shared__ float red[4];

    float4 v = make_float4(-1e30f, -1e30f, -1e30f, -1e30f);
    if (ok) v = ((const float4*)row)[tid];
    float m = fmaxf(fmaxf(v.x, v.y), fmaxf(v.z, v.w));
    #pragma unroll
    for (int o = 1; o < 64; o <<= 1) m = fmaxf(m, __shfl_xor(m, o, 64));
    if ((tid & 63) == 0) red[tid >> 6] = m;
    __syncthreads();
    m = fmaxf(fmaxf(red[0], red[1]), fmaxf(red[2], red[3]));
    __syncthreads();

    float4 e;
    e.x = ok ? __expf(v.x - m) : 0.f;
    e.y = ok ? __expf(v.y - m) : 0.f;
    e.z = ok ? __expf(v.z - m) : 0.f;
    e.w = ok ? __expf(v.w - m) : 0.f;
    float s = e.x + e.y + e.z + e.w;
    #pragma unroll
    for (int o = 1; o < 64; o <<= 1) s += __shfl_xor(s, o, 64);
    if ((tid & 63) == 0) red[tid >> 6] = s;
    __syncthreads();
    s = red[0] + red[1] + red[2] + red[3];
    float inv = 1.f / s;
    if (ok) {
        e.x *= inv; e.y *= inv; e.z *= inv; e.w *= inv;
        ushort4 h, l;
        h.x = bf16_rne(e.x); l.x = bf16_rne(e.x - bf16_f(h.x));
        h.y = bf16_rne(e.y); l.y = bf16_rne(e.y - bf16_f(h.y));
        h.z = bf16_rne(e.z); l.z = bf16_rne(e.z - bf16_f(h.z));
        h.w = bf16_rne(e.w); l.w = bf16_rne(e.w - bf16_f(h.w));
        *(ushort4*)(dhi + tid * 4) = h;
        *(ushort4*)(dlo + tid * 4) = l;
    }
}

// ---------------------------------------------------------------------------
// att GEMMs via MFMA: out[c][n] = sum_k F[c][k] * S[n][k].
// z&7=img, z>>3: 0 -> f2_att = f1 . ST  (out slot 8+img)
//                1 -> f1_att = f2 . SR  (out slot img)
// M=128, N-tile=48, K=784 in 13 chunks of 64 (zero-padded).
// ---------------------------------------------------------------------------
__global__ __launch_bounds__(256, 2) void k_att_mfma(
    const u16* __restrict__ Fhi, const u16* __restrict__ Flo,
    const u16* __restrict__ SRhi, const u16* __restrict__ SRlo,
    const u16* __restrict__ SThi, const u16* __restrict__ STlo,
    float* __restrict__ fatt)
{
    __shared__ u16 As[2][128][64];   // 32 KB
    __shared__ u16 Bs[2][48][64];    // 12 KB
    const int z = blockIdx.z;
    const int img = z & 7, which = z >> 3;
    const u16* pA0 = Fhi + (size_t)(which ? 8 + img : img) * Cc * HWc;
    const u16* pA1 = Flo + (size_t)(which ? 8 + img : img) * Cc * HWc;
    const u16* pB0 = (which ? SRhi : SThi) + (size_t)img * HWc * HWc;
    const u16* pB1 = (which ? SRlo : STlo) + (size_t)img * HWc * HWc;
    float* out = fatt + (size_t)(which ? img : 8 + img) * Cc * HWc;
    const int n0 = blockIdx.x * 48;
    const int tid = threadIdx.x;
    const int wid = tid >> 6, lane = tid & 63;
    const int lhi = lane >> 4, llo = lane & 15;

    f32x4 acc[2][3];
    #pragma unroll
    for (int s = 0; s < 2; ++s)
        #pragma unroll
        for (int n = 0; n < 3; ++n)
            acc[s][n] = f32x4{0.f, 0.f, 0.f, 0.f};

    for (int kc = 0; kc < 13; ++kc) {
        const int k0 = kc * 64;
        if (kc) __syncthreads();
        #pragma unroll
        for (int j = 0; j < 8; ++j) {
            int idx = tid + j * 256;
            int chunk = idx & 7, row = (idx >> 3) & 127, comp = idx >> 10;
            u16x8 v = {0, 0, 0, 0, 0, 0, 0, 0};
            if (k0 + chunk * 8 < HWc) {
                const u16* src = comp ? pA1 : pA0;
                v = *(const u16x8*)(src + (size_t)row * HWc + k0 + chunk * 8);
            }
            *(u16x8*)&As[comp][row][(chunk ^ (row & 7)) * 8] = v;
        }
        #pragma unroll
        for (int j = 0; j < 3; ++j) {
            int idx = tid + j * 256;
            int chunk = idx & 7, row = (idx >> 3) % 48, comp = idx / 384;
            u16x8 v = {0, 0, 0, 0, 0, 0, 0, 0};
            int n = n0 + row;
            if (n < HWc && k0 + chunk * 8 < HWc) {
                const u16* src = comp ? pB1 : pB0;
                v = *(const u16x8*)(src + (size_t)n * HWc + k0 + chunk * 8);
            }
            *(u16x8*)&Bs[comp][row][(chunk ^ (row & 7)) * 8] = v;
        }
        __syncthreads();
        #pragma unroll
        for (int ks = 0; ks < 2; ++ks) {
            bf16x8 ah[2], al[2];
            #pragma unroll
            for (int s = 0; s < 2; ++s) {
                int row = wid * 32 + s * 16 + llo;
                int ch = (ks * 4 + lhi) ^ (row & 7);
                ah[s] = *(const bf16x8*)&As[0][row][ch * 8];
                al[s] = *(const bf16x8*)&As[1][row][ch * 8];
            }
            #pragma unroll
            for (int ni = 0; ni < 3; ++ni) {
                int row = ni * 16 + llo;
                int ch = (ks * 4 + lhi) ^ (row & 7);
                bf16x8 bh = *(const bf16x8*)&Bs[0][row][ch * 8];
                bf16x8 bl = *(const bf16x8*)&Bs[1][row][ch * 8];
                #pragma unroll
                for (int s = 0; s < 2; ++s) {
                    acc[s][ni] = __builtin_amdgcn_mfma_f32_16x16x32_bf16(ah[s], bh, acc[s][ni], 0, 0, 0);
                    acc[s][ni] = __builtin_amdgcn_mfma_f32_16x16x32_bf16(ah[s], bl, acc[s][ni], 0, 0, 0);
                    acc[s][ni] = __builtin_amdgcn_mfma_f32_16x16x32_bf16(al[s], bh, acc[s][ni], 0, 0, 0);
                }
            }
        }
    }

    #pragma unroll
    for (int s = 0; s < 2; ++s) {
        #pragma unroll
        for (int r = 0; r < 4; ++r) {
            int m = wid * 32 + s * 16 + lhi * 4 + r;  // channel, < 128
            #pragma unroll
            for (int ni = 0; ni < 3; ++ni) {
                int n = n0 + ni * 16 + llo;
                if (n < HWc) out[(size_t)m * HWc + n] = acc[s][ni][r];
            }
        }
    }
}

// ---------------------------------------------------------------------------
// MFMA split-bf16 classifier (unchanged from round 1/3)
// ---------------------------------------------------------------------------
__global__ __launch_bounds__(256, 2) void k_l2_mfma(
    const u16* __restrict__ xthi, const u16* __restrict__ xtlo,  // [48][784][128]
    const u16* __restrict__ phi,  const u16* __restrict__ plo,   // [2000][128]
    const u16* __restrict__ phie, const u16* __restrict__ ploe,
    const float* __restrict__ p2,  const float* __restrict__ p2e,
    const float* __restrict__ x2all,                              // [48][784]
    float* __restrict__ out, float* __restrict__ mdatt, float* __restrict__ mdaug)
{
    __shared__ u16 As[2][128][64];
    __shared__ u16 Bs[2][112][64];
    const int img = blockIdx.z;
    const int p0 = blockIdx.y * 128;
    const int n0 = blockIdx.x * 112;
    const int tid = threadIdx.x;
    const int wid = tid >> 6, lane = tid & 63;
    const int lhi = lane >> 4, llo = lane & 15;

    const u16* pA0 = (img < 32) ? phi : phie;
    const u16* pA1 = (img < 32) ? plo : ploe;
    const u16* pB0 = xthi + (size_t)img * HWc * Cc;
    const u16* pB1 = xtlo + (size_t)img * HWc * Cc;

    f32x4 acc[2][7];
    #pragma unroll
    for (int s = 0; s < 2; ++s)
        #pragma unroll
        for (int n = 0; n < 7; ++n)
            acc[s][n] = f32x4{0.f, 0.f, 0.f, 0.f};

    for (int kc = 0; kc < 2; ++kc) {
        const int k0 = kc * 64;
        if (kc) __syncthreads();
        #pragma unroll
        for (int j = 0; j < 8; ++j) {
            int idx = tid + j * 256;
            int chunk = idx & 7, row = (idx >> 3) & 127, comp = idx >> 10;
            u16x8 v = {0, 0, 0, 0, 0, 0, 0, 0};
            int p = p0 + row;
            if (p < Pc) {
                const u16* src = comp ? pA1 : pA0;
                v = *(const u16x8*)(src + (size_t)p * Cc + k0 + chunk * 8);
            }
            *(u16x8*)&As[comp][row][(chunk ^ (row & 7)) * 8] = v;
        }
        #pragma unroll
        for (int j = 0; j < 7; ++j) {
            int idx = tid + j * 256;
            int chunk = idx & 7, row = (idx >> 3) % 112, comp = idx / 896;
            const u16* src = comp ? pB1 : pB0;
            u16x8 v = *(const u16x8*)(src + (size_t)(n0 + row) * Cc + k0 + chunk * 8);
            *(u16x8*)&Bs[comp][row][(chunk ^ (row & 7)) * 8] = v;
        }
        __syncthreads();
        #pragma unroll
        for (int ks = 0; ks < 2; ++ks) {
            bf16x8 ah[2], al[2];
            #pragma unroll
            for (int s = 0; s < 2; ++s) {
                int row = wid * 32 + s * 16 + llo;
                int ch = (ks * 4 + lhi) ^ (row & 7);
                ah[s] = *(const bf16x8*)&As[0][row][ch * 8];
                al[s] = *(const bf16x8*)&As[1][row][ch * 8];
            }
            #pragma unroll
            for (int ni = 0; ni < 7; ++ni) {
                int row = ni * 16 + llo;
                int ch = (ks * 4 + lhi) ^ (row & 7);
                bf16x8 bh = *(const bf16x8*)&Bs[0][row][ch * 8];
                bf16x8 bl = *(const bf16x8*)&Bs[1][row][ch * 8];
                #pragma unroll
                for (int s = 0; s < 2; ++s) {
                    acc[s][ni] = __builtin_amdgcn_mfma_f32_16x16x32_bf16(ah[s], bh, acc[s][ni], 0, 0, 0);
                    acc[s][ni] = __builtin_amdgcn_mfma_f32_16x16x32_bf16(ah[s], bl, acc[s][ni], 0, 0, 0);
                    acc[s][ni] = __builtin_amdgcn_mfma_f32_16x16x32_bf16(al[s], bh, acc[s][ni], 0, 0, 0);
                }
            }
        }
    }

    // epilogue
    const float* x2i = x2all + (long)img * HWc;
    const float* p2p = (img < 32) ? p2 : p2e;
    float* simp = nullptr;
    if (img < 16) simp = out + OFF_SIM + (size_t)img * Pc * HWc;
    else if (img >= 32) simp = out + OFF_SIME + (size_t)(img - 32) * Pc * HWc;
    float* mdp = (img < 16) ? out + OFF_MD + (long)img * Pc
               : (img < 32) ? mdatt + (long)(img - 16) * Pc
                            : mdaug + (long)(img - 32) * Pc;

    #pragma unroll
    for (int s = 0; s < 2; ++s) {
        const int mbase = p0 + wid * 32 + s * 16 + lhi * 4;
        float p2v[4], dmin[4];
        bool mok[4];
        #pragma unroll
        for (int r = 0; r < 4; ++r) {
            int m = mbase + r;
            mok[r] = m < Pc;
            p2v[r] = mok[r] ? p2p[m] : 0.f;
            dmin[r] = 1e30f;
        }
        #pragma unroll
        for (int ni = 0; ni < 7; ++ni) {
            int hw = n0 + ni * 16 + llo;
            float x2v = x2i[hw];
            #pragma unroll
            for (int r = 0; r < 4; ++r) {
                float d = fmaxf(fmaf(-2.f, acc[s][ni][r], x2v + p2v[r]), 0.f);
                dmin[r] = fminf(dmin[r], d);
                if (simp != nullptr && mok[r])
                    simp[(size_t)(mbase + r) * HWc + hw] = __expf(d * (-1.f / 256.f));
            }
        }
        #pragma unroll
        for (int r = 0; r < 4; ++r) {
            float v = dmin[r];
            v = fminf(v, __shfl_xor(v, 1, 64));
            v = fminf(v, __shfl_xor(v, 2, 64));
            v = fminf(v, __shfl_xor(v, 4, 64));
            v = fminf(v, __shfl_xor(v, 8, 64));
            if (llo == 0 && mok[r])
                atomicMin((int*)(mdp + mbase + r), __float_as_int(v));
        }
    }
}

// ---------------------------------------------------------------------------
// all 48 logits rows in one dispatch
// ---------------------------------------------------------------------------
__global__ __launch_bounds__(256) void k_logits_all(
    float* __restrict__ out,
    const float* __restrict__ mdatt, const float* __restrict__ mdaug,
    const float* __restrict__ wl, const float* __restrict__ wle)
{
    const int b = blockIdx.x;
    const float* md; const float* w; float* dst;
    if (b < 16)      { md = out + OFF_MD + (long)b * Pc;          w = wl;  dst = out + OFF_SCORE + (long)b * NCc; }
    else if (b < 32) { md = mdatt + (long)(b - 16) * Pc;          w = wl;  dst = out + OFF_CO + (long)(b - 16) * NCc; }
    else             { md = mdaug + (long)(b - 32) * Pc;          w = wle; dst = out + OFF_LOGE + (long)(b - 32) * NCc; }

    __shared__ __align__(16) float act[Pc];
    for (int p = threadIdx.x; p < Pc; p += 256)
        act[p] = __expf(md[p] * (-1.f / 256.f));
    __syncthreads();
    const int c = threadIdx.x;
    if (c < NCc) {
        const float4* wrow = (const float4*)(w + (long)c * Pc);
        const float4* arow = (const float4*)act;
        float s = 0.f;
        for (int q = 0; q < Pc / 4; ++q) {
            float4 wv = wrow[q];
            float4 av = arow[q];
            s += wv.x * av.x + wv.y * av.y + wv.z * av.z + wv.w * av.w;
        }
        dst[c] = s;
    }
}

// ---------------------------------------------------------------------------
extern "C" void kernel_launch(void* const* d_in, const int* in_sizes, int n_in,
                              void* d_out, int out_size, void* d_ws, size_t ws_size,
                              hipStream_t stream) {
    const float* f1    = (const float*)d_in[0];
    const float* f2    = (const float*)d_in[1];
    const float* faug  = (const float*)d_in[2];
    const float* prot  = (const float*)d_in[3];
    const float* prote = (const float*)d_in[4];
    const float* wl    = (const float*)d_in[5];
    const float* wle   = (const float*)d_in[6];
    float* out = (float*)d_out;
    float* ws  = (float*)d_ws;

    // workspace layout (float offsets)
    float* A2buf = ws;                      // 8*784*784
    float* A2T   = ws + 4917248;            // 8*784*784
    float* fatt  = ws + 9834496;            // 16*128*784 (f1_att 0-7, f2_att 8-15)
    float* x2all = ws + 11440128;           // 48*784
    float* p2    = ws + 11477760;           // 2000
    float* p2e   = ws + 11479760;           // 2000
    float* mdatt = ws + 11481760;           // 16*2000
    float* mdaug = ws + 11513760;           // 16*2000
    u16* phi  = (u16*)(ws + 11545760);      // 2000*128
    u16* plo  = (u16*)(ws + 11673760);
    u16* phie = (u16*)(ws + 11801760);
    u16* ploe = (u16*)(ws + 11929760);
    u16* xthi = (u16*)(ws + 12057760);      // 48*784*128 u16
    u16* xtlo = (u16*)(ws + 14466208);
    u16* SRhi = (u16*)(ws + 16874656);      // 8*784*784 u16 each
    u16* SRlo = (u16*)(ws + 19333280);
    u16* SThi = (u16*)(ws + 21791904);
    u16* STlo = (u16*)(ws + 24250528);
    u16* Fbhi = (u16*)(ws + 26709152);      // 16*128*784 u16
    u16* Fblo = (u16*)(ws + 27511968);      // ends 28314784 floats (~113 MB)

    constexpr size_t IS = (size_t)HWc * Cc;  // per-image bf16 stride
    constexpr int NPER = 8 * Cc * HWc;       // 802816

    // init md accumulators
    k_init3<<<(32000 + 255) / 256, 256, 0, stream>>>(out + OFF_MD, mdatt, mdaug, 32000, 1e30f);
    // proto norms + conversions
    k_p2<<<(2 * Pc + 255) / 256, 256, 0, stream>>>(prot, prote, p2, p2e);
    k_cvt_prot<<<(2 * Pc * Cc + 255) / 256, 256, 0, stream>>>(prot, prote, phi, plo, phie, ploe);
    // x norms
    k_x2<<<(8 * HWc + 255) / 256, 256, 0, stream>>>(f1, x2all, 8);
    k_x2<<<(8 * HWc + 255) / 256, 256, 0, stream>>>(f2, x2all + 8 * HWc, 8);
    k_x2<<<(16 * HWc + 255) / 256, 256, 0, stream>>>(faug, x2all + 32 * HWc, 16);
    // x conversions (transpose to [img][hw][c], bf16 hi/lo)
    dim3 cb(32, 8);
    k_cvt_x<<<dim3(25, 4, 8), cb, 0, stream>>>(f1, xthi, xtlo);
    k_cvt_x<<<dim3(25, 4, 8), cb, 0, stream>>>(f2, xthi + 8 * IS, xtlo + 8 * IS);
    k_cvt_x<<<dim3(25, 4, 16), cb, 0, stream>>>(faug, xthi + 32 * IS, xtlo + 32 * IS);
    // flat conversions for att-GEMM A operands
    k_cvt_flat4<<<(2 * NPER / 4 + 255) / 256, 256, 0, stream>>>(
        (const float4*)f1, (const float4*)f2, (ushort4*)Fbhi, (ushort4*)Fblo, NPER / 4);

    // ---- attention path (MFMA split-bf16) ----
    k_a2_mfma<<<dim3(7, 7, 16), 256, 0, stream>>>(xthi, xtlo, A2buf, A2T);
    k_smax_row_bf16<<<dim3(HWc, 8, 2), 256, 0, stream>>>(A2buf, A2T, SRhi, SRlo, SThi, STlo);
    k_att_mfma<<<dim3(17, 1, 16), 256, 0, stream>>>(Fbhi, Fblo, SRhi, SRlo, SThi, STlo, fatt);

    k_x2<<<(16 * HWc + 255) / 256, 256, 0, stream>>>(fatt, x2all + 16 * HWc, 16);
    k_cvt_x<<<dim3(25, 4, 16), cb, 0, stream>>>(fatt, xthi + 16 * IS, xtlo + 16 * IS);

    // ---- fused MFMA classifier over all 48 images ----
    k_l2_mfma<<<dim3(7, 16, 48), 256, 0, stream>>>(
        xthi, xtlo, phi, plo, phie, ploe, p2, p2e, x2all, out, mdatt, mdaug);

    // ---- logits ----
    k_logits_all<<<48, 256, 0, stream>>>(out, mdatt, mdaug, wl, wle);
}